// Round 2
// baseline (1050.133 us; speedup 1.0000x reference)
//
#include <hip/hip_runtime.h>
#include <math.h>

#define C 64
#define K 20

#define P1_TPB 128
#define P1_ROWS 128
#define LSTR 65          // 64 + 1 pad: (row*65 + k) % 32 = (row + k) % 32 -> 2-way = free
#define P2_TPB 256

// ---------------- helpers ----------------

__device__ __forceinline__ float wave_reduce_add(float v) {
#pragma unroll
  for (int m = 32; m > 0; m >>= 1) v += __shfl_xor(v, m, 64);
  return v;
}

__device__ __forceinline__ unsigned short f2bf16(float x) {
  union { float f; unsigned u; } v; v.f = x;
  unsigned r = v.u + 0x7FFFu + ((v.u >> 16) & 1u);   // round-to-nearest-even
  return (unsigned short)(r >> 16);
}

__device__ __forceinline__ float bf16lo(unsigned u) { return __uint_as_float(u << 16); }
__device__ __forceinline__ float bf16hi(unsigned u) { return __uint_as_float(u & 0xFFFF0000u); }

// per-point L1 / cosine losses
__device__ __forceinline__ void point_losses(long long p, float bp0, float bp1, float bp2,
                                             const float* __restrict__ coord,
                                             const int* __restrict__ instance,
                                             const float* __restrict__ centroid,
                                             float& l1m, float& cosm, float& m) {
  float cx = coord[p * 3 + 0], cy = coord[p * 3 + 1], cz = coord[p * 3 + 2];
  float gx = centroid[p * 3 + 0] - cx;
  float gy = centroid[p * 3 + 1] - cy;
  float gz = centroid[p * 3 + 2] - cz;
  m = (instance[p] != -1) ? 1.0f : 0.0f;
  float l1 = fabsf(bp0 - gx) + fabsf(bp1 - gy) + fabsf(bp2 - gz);
  float npn = sqrtf(bp0 * bp0 + bp1 * bp1 + bp2 * bp2) + 1e-8f;
  float ngn = sqrtf(gx * gx + gy * gy + gz * gz) + 1e-8f;
  float cs = -(bp0 * gx + bp1 * gy + bp2 * gz) / (npn * ngn);
  l1m = l1 * m;
  cosm = cs * m;
}

// acc layout (floats): [0]=sum w*nll  [1]=sum w  [2]=sum l1*m  [3]=sum cos*m  [4]=sum m
//                      [8..71]=sum_h per channel  [72..135]=sum_h2 per channel

// ---------------- pass 1: h-GEMM + BN stats + seg loss + bf16 h spill ----------------

__global__ __launch_bounds__(P1_TPB, 2)
void pass1_kernel(const float* __restrict__ feat,
                  const int* __restrict__ segment,
                  const float* __restrict__ W1,
                  const float* __restrict__ b1,
                  const float* __restrict__ Wseg,
                  const float* __restrict__ bseg,
                  const float* __restrict__ cw,
                  float* __restrict__ acc,
                  unsigned short* __restrict__ hout,
                  int store_h, int n) {
  __shared__ float lds[P1_ROWS * LSTR];
  __shared__ float wpart[2][2];
  __shared__ float cpart[2][2][C];

  const int tid = threadIdx.x;
  const int wave = tid >> 6;
  const int lane = tid & 63;
  const long long base = (long long)blockIdx.x * P1_ROWS;

  // stage feat tile (coalesced float4) into padded LDS rows
  {
    const float4* src = (const float4*)(feat + base * C);
#pragma unroll
    for (int i = 0; i < 16; ++i) {
      int g = tid + i * P1_TPB;
      float4 v = src[g];
      int pr = g >> 4;
      int c = (g & 15) << 2;
      float* d = &lds[pr * LSTR + c];
      d[0] = v.x; d[1] = v.y; d[2] = v.z; d[3] = v.w;
    }
  }
  __syncthreads();

  // dual GEMM: h[64] and logits[20]; weights come in as uniform (scalar) loads
  float h[C], lg[K];
#pragma unroll
  for (int j = 0; j < C; ++j) h[j] = b1[j];
#pragma unroll
  for (int c = 0; c < K; ++c) lg[c] = bseg[c];
  const float* frow = &lds[tid * LSTR];
#pragma unroll 4
  for (int k = 0; k < C; ++k) {
    float fk = frow[k];
#pragma unroll
    for (int j = 0; j < C; ++j) h[j] = __builtin_fmaf(fk, W1[k * C + j], h[j]);
#pragma unroll
    for (int c = 0; c < K; ++c) lg[c] = __builtin_fmaf(fk, Wseg[k * K + c], lg[c]);
  }

  // weighted cross-entropy contribution (torch semantics, ignore_index=-1)
  {
    const long long p = base + tid;
    const int seg = segment[p];
    const bool valid = (seg != -1);
    const int tgt = valid ? seg : 0;
    float mx = lg[0], lt = lg[0];
#pragma unroll
    for (int c = 1; c < K; ++c) {
      mx = fmaxf(mx, lg[c]);
      lt = (c == tgt) ? lg[c] : lt;
    }
    float se = 0.0f;
#pragma unroll
    for (int c = 0; c < K; ++c) se += __expf(lg[c] - mx);
    float nll = mx + __logf(se) - lt;
    float w = valid ? cw[tgt] : 0.0f;
    float rwn = wave_reduce_add(w * nll);
    float rw = wave_reduce_add(w);
    if (lane == 0) { wpart[wave][0] = rwn; wpart[wave][1] = rw; }
  }

  // reuse LDS: store h rows for channel-stat column sums + coalesced bf16 spill
  __syncthreads();
#pragma unroll
  for (int j = 0; j < C; ++j) lds[tid * LSTR + j] = h[j];
  __syncthreads();

  // column sums: wave w reduces 64 rows for channel `lane`
  {
    float s = 0.0f, s2 = 0.0f;
    const int r0 = wave * 64;
#pragma unroll 8
    for (int r = r0; r < r0 + 64; ++r) {
      float v = lds[r * LSTR + lane];
      s += v;
      s2 = __builtin_fmaf(v, v, s2);
    }
    cpart[wave][0][lane] = s;
    cpart[wave][1][lane] = s2;
  }

  // bf16 h spill, coalesced (8B/lane)
  if (store_h) {
#pragma unroll
    for (int i = 0; i < 16; ++i) {
      int g = tid + i * P1_TPB;
      int pr = g >> 4;
      int c = (g & 15) << 2;
      const float* s4 = &lds[pr * LSTR + c];
      ushort4 o;
      o.x = f2bf16(s4[0]); o.y = f2bf16(s4[1]); o.z = f2bf16(s4[2]); o.w = f2bf16(s4[3]);
      *(ushort4*)(hout + base * C + (long long)g * 4) = o;
    }
  }
  __syncthreads();

  if (tid == 0) {
    atomicAdd(&acc[0], wpart[0][0] + wpart[1][0]);
    atomicAdd(&acc[1], wpart[0][1] + wpart[1][1]);
  }
  if (tid < C) {
    atomicAdd(&acc[8 + tid], cpart[0][0][tid] + cpart[1][0][tid]);
    atomicAdd(&acc[72 + tid], cpart[0][1][tid] + cpart[1][1][tid]);
  }
}

// ---------------- pass 2 (fast path): BN+ReLU+GEMV from bf16 h ----------------

__global__ __launch_bounds__(P2_TPB, 4)
void pass2_from_h(const unsigned short* __restrict__ hsrc,
                  const float* __restrict__ coord,
                  const int* __restrict__ instance,
                  const float* __restrict__ centroid,
                  const float* __restrict__ gamma,
                  const float* __restrict__ beta,
                  const float* __restrict__ W2,
                  const float* __restrict__ b2,
                  float* acc, int n) {
  __shared__ float ssc[C], ssh[C];
  __shared__ float part[4][3];
  const int tid = threadIdx.x;
  const int wave = tid >> 6;
  const int lane = tid & 63;

  if (tid < C) {
    float inv_n = 1.0f / (float)n;
    float mean = acc[8 + tid] * inv_n;
    float var = fmaxf(acc[72 + tid] * inv_n - mean * mean, 0.0f);
    float sc = gamma[tid] * rsqrtf(var + 1e-3f);
    ssc[tid] = sc;
    ssh[tid] = beta[tid] - mean * sc;
  }
  __syncthreads();

  const long long p = (long long)blockIdx.x * P2_TPB + tid;
  const uint4* hv = (const uint4*)(hsrc + p * C);
  float bp0 = b2[0], bp1 = b2[1], bp2 = b2[2];
#pragma unroll
  for (int i = 0; i < 8; ++i) {
    uint4 q = hv[i];
    unsigned qs[4] = { q.x, q.y, q.z, q.w };
#pragma unroll
    for (int u = 0; u < 4; ++u) {
      int j = i * 8 + u * 2;
      float v0 = bf16lo(qs[u]);
      float v1 = bf16hi(qs[u]);
      float y0 = fmaxf(__builtin_fmaf(v0, ssc[j], ssh[j]), 0.0f);
      float y1 = fmaxf(__builtin_fmaf(v1, ssc[j + 1], ssh[j + 1]), 0.0f);
      bp0 = __builtin_fmaf(y0, W2[j * 3 + 0], bp0);
      bp1 = __builtin_fmaf(y0, W2[j * 3 + 1], bp1);
      bp2 = __builtin_fmaf(y0, W2[j * 3 + 2], bp2);
      bp0 = __builtin_fmaf(y1, W2[(j + 1) * 3 + 0], bp0);
      bp1 = __builtin_fmaf(y1, W2[(j + 1) * 3 + 1], bp1);
      bp2 = __builtin_fmaf(y1, W2[(j + 1) * 3 + 2], bp2);
    }
  }

  float l1m, cosm, m;
  point_losses(p, bp0, bp1, bp2, coord, instance, centroid, l1m, cosm, m);
  float r0 = wave_reduce_add(l1m);
  float r1 = wave_reduce_add(cosm);
  float r2 = wave_reduce_add(m);
  if (lane == 0) { part[wave][0] = r0; part[wave][1] = r1; part[wave][2] = r2; }
  __syncthreads();
  if (tid == 0) {
    float a0 = 0, a1 = 0, a2 = 0;
#pragma unroll
    for (int wv = 0; wv < 4; ++wv) { a0 += part[wv][0]; a1 += part[wv][1]; a2 += part[wv][2]; }
    atomicAdd(&acc[2], a0);
    atomicAdd(&acc[3], a1);
    atomicAdd(&acc[4], a2);
  }
}

// ---------------- pass 2 (fallback): recompute h from feat ----------------

__global__ __launch_bounds__(P1_TPB, 2)
void pass2_recompute(const float* __restrict__ feat,
                     const float* __restrict__ coord,
                     const int* __restrict__ instance,
                     const float* __restrict__ centroid,
                     const float* __restrict__ W1,
                     const float* __restrict__ b1,
                     const float* __restrict__ gamma,
                     const float* __restrict__ beta,
                     const float* __restrict__ W2,
                     const float* __restrict__ b2,
                     float* acc, int n) {
  __shared__ float lds[P1_ROWS * LSTR];
  __shared__ float ssc[C], ssh[C];
  __shared__ float part[2][3];
  const int tid = threadIdx.x;
  const int wave = tid >> 6;
  const int lane = tid & 63;
  const long long base = (long long)blockIdx.x * P1_ROWS;

  if (tid < C) {
    float inv_n = 1.0f / (float)n;
    float mean = acc[8 + tid] * inv_n;
    float var = fmaxf(acc[72 + tid] * inv_n - mean * mean, 0.0f);
    float sc = gamma[tid] * rsqrtf(var + 1e-3f);
    ssc[tid] = sc;
    ssh[tid] = beta[tid] - mean * sc;
  }
  {
    const float4* src = (const float4*)(feat + base * C);
#pragma unroll
    for (int i = 0; i < 16; ++i) {
      int g = tid + i * P1_TPB;
      float4 v = src[g];
      int pr = g >> 4;
      int c = (g & 15) << 2;
      float* d = &lds[pr * LSTR + c];
      d[0] = v.x; d[1] = v.y; d[2] = v.z; d[3] = v.w;
    }
  }
  __syncthreads();

  float h[C];
#pragma unroll
  for (int j = 0; j < C; ++j) h[j] = b1[j];
  const float* frow = &lds[tid * LSTR];
#pragma unroll 4
  for (int k = 0; k < C; ++k) {
    float fk = frow[k];
#pragma unroll
    for (int j = 0; j < C; ++j) h[j] = __builtin_fmaf(fk, W1[k * C + j], h[j]);
  }

  float bp0 = b2[0], bp1 = b2[1], bp2 = b2[2];
#pragma unroll
  for (int j = 0; j < C; ++j) {
    float y = fmaxf(__builtin_fmaf(h[j], ssc[j], ssh[j]), 0.0f);
    bp0 = __builtin_fmaf(y, W2[j * 3 + 0], bp0);
    bp1 = __builtin_fmaf(y, W2[j * 3 + 1], bp1);
    bp2 = __builtin_fmaf(y, W2[j * 3 + 2], bp2);
  }

  const long long p = base + tid;
  float l1m, cosm, m;
  point_losses(p, bp0, bp1, bp2, coord, instance, centroid, l1m, cosm, m);
  float r0 = wave_reduce_add(l1m);
  float r1 = wave_reduce_add(cosm);
  float r2 = wave_reduce_add(m);
  if (lane == 0) { part[wave][0] = r0; part[wave][1] = r1; part[wave][2] = r2; }
  __syncthreads();
  if (tid == 0) {
    float a0 = part[0][0] + part[1][0];
    float a1 = part[0][1] + part[1][1];
    float a2 = part[0][2] + part[1][2];
    atomicAdd(&acc[2], a0);
    atomicAdd(&acc[3], a1);
    atomicAdd(&acc[4], a2);
  }
}

// ---------------- finalize ----------------

__global__ void finalize_kernel(const float* __restrict__ acc, float* __restrict__ out) {
  if (threadIdx.x == 0 && blockIdx.x == 0) {
    float seg = acc[0] / acc[1];
    float den = acc[4] + 1e-8f;
    float l1 = acc[2] / den;
    float cs = acc[3] / den;
    out[0] = seg + l1 + cs;
    out[1] = seg;
    out[2] = l1;
    out[3] = cs;
  }
}

// ---------------- launch ----------------

extern "C" void kernel_launch(void* const* d_in, const int* in_sizes, int n_in,
                              void* d_out, int out_size, void* d_ws, size_t ws_size,
                              hipStream_t stream) {
  const float* feat = (const float*)d_in[0];
  const float* coord = (const float*)d_in[1];
  const int* segment = (const int*)d_in[2];
  const int* instance = (const int*)d_in[3];
  const float* centroid = (const float*)d_in[4];
  const float* W1 = (const float*)d_in[5];
  const float* b1 = (const float*)d_in[6];
  const float* gamma = (const float*)d_in[7];
  const float* beta = (const float*)d_in[8];
  const float* W2 = (const float*)d_in[9];
  const float* b2 = (const float*)d_in[10];
  const float* Wseg = (const float*)d_in[11];
  const float* bseg = (const float*)d_in[12];
  const float* cw = (const float*)d_in[13];

  const int n = in_sizes[0] / C;  // 1048576; divisible by 256 in this problem

  float* acc = (float*)d_ws;
  unsigned short* hbuf = (unsigned short*)((char*)d_ws + 1024);
  const size_t need = 1024 + (size_t)n * C * sizeof(unsigned short);
  const int store_h = (ws_size >= need) ? 1 : 0;

  size_t zbytes = ws_size < 1024 ? ws_size : 1024;
  hipMemsetAsync(d_ws, 0, zbytes, stream);  // zero the accumulator block (ws is poisoned 0xAA)

  pass1_kernel<<<n / P1_ROWS, P1_TPB, 0, stream>>>(feat, segment, W1, b1, Wseg, bseg, cw,
                                                   acc, hbuf, store_h, n);
  if (store_h) {
    pass2_from_h<<<n / P2_TPB, P2_TPB, 0, stream>>>(hbuf, coord, instance, centroid,
                                                    gamma, beta, W2, b2, acc, n);
  } else {
    pass2_recompute<<<n / P1_ROWS, P1_TPB, 0, stream>>>(feat, coord, instance, centroid,
                                                        W1, b1, gamma, beta, W2, b2, acc, n);
  }
  finalize_kernel<<<1, 1, 0, stream>>>(acc, (float*)d_out);
}

// Round 3
// 695.386 us; speedup vs baseline: 1.5101x; 1.5101x over previous
//
#include <hip/hip_runtime.h>
#include <math.h>

#define C 64
#define K 20
#define MT 256        // points per MFMA block
#define ASTR 72       // A/B LDS row stride (bf16 units): frag b128 reads 2-way = free
#define HSTR 68       // h LDS stride (bf16): b64 rw, 8B-aligned
#define LGSTR 22      // logit LDS stride (bf16)

// fallback (recompute) path constants
#define P1_TPB 128
#define P1_ROWS 128
#define LSTR 65

typedef __attribute__((ext_vector_type(8))) short bf16x8;
typedef __attribute__((ext_vector_type(4))) float f32x4;

// ---------------- helpers ----------------

__device__ __forceinline__ float wave_reduce_add(float v) {
#pragma unroll
  for (int m = 32; m > 0; m >>= 1) v += __shfl_xor(v, m, 64);
  return v;
}

__device__ __forceinline__ unsigned short f2bf16(float x) {
  union { float f; unsigned u; } v; v.f = x;
  unsigned r = v.u + 0x7FFFu + ((v.u >> 16) & 1u);   // RTNE
  return (unsigned short)(r >> 16);
}

__device__ __forceinline__ float bf16lo(unsigned u) { return __uint_as_float(u << 16); }
__device__ __forceinline__ float bf16hi(unsigned u) { return __uint_as_float(u & 0xFFFF0000u); }

__device__ __forceinline__ void point_losses(long long p, float bp0, float bp1, float bp2,
                                             const float* __restrict__ coord,
                                             const int* __restrict__ instance,
                                             const float* __restrict__ centroid,
                                             float& l1m, float& cosm, float& m) {
  float cx = coord[p * 3 + 0], cy = coord[p * 3 + 1], cz = coord[p * 3 + 2];
  float gx = centroid[p * 3 + 0] - cx;
  float gy = centroid[p * 3 + 1] - cy;
  float gz = centroid[p * 3 + 2] - cz;
  m = (instance[p] != -1) ? 1.0f : 0.0f;
  float l1 = fabsf(bp0 - gx) + fabsf(bp1 - gy) + fabsf(bp2 - gz);
  float npn = sqrtf(bp0 * bp0 + bp1 * bp1 + bp2 * bp2) + 1e-8f;
  float ngn = sqrtf(gx * gx + gy * gy + gz * gz) + 1e-8f;
  float cs = -(bp0 * gx + bp1 * gy + bp2 * gz) / (npn * ngn);
  l1m = l1 * m;
  cosm = cs * m;
}

// acc layout (floats): [0]=sum w*nll [1]=sum w [2]=sum l1*m [3]=sum cos*m [4]=sum m
// [8..71]=sum_h  [72..135]=sum_h2  [136..199]=BN scale  [200..263]=BN shift

// ---------------- pass 1: MFMA dual-GEMM + BN stats + CE + bf16 h spill ----------------
// b1 is dropped: BatchNorm(train) output is invariant to a constant channel shift.

__global__ __launch_bounds__(256)
void pass1_kernel(const float* __restrict__ feat,
                  const int* __restrict__ segment,
                  const float* __restrict__ W1,
                  const float* __restrict__ Wseg,
                  const float* __restrict__ bseg,
                  const float* __restrict__ cw,
                  float* __restrict__ acc,
                  unsigned short* __restrict__ hout,
                  int store_h, int n) {
  __shared__ __align__(16) char smem[52768];
  unsigned short* As  = (unsigned short*)smem;             // [256][72] bf16 feat tile
  unsigned short* Bs  = (unsigned short*)(smem + 36864);   // [96][72] bf16: W1^T rows 0..63, Wseg^T rows 64..95
  float* cs1   = (float*)(smem + 50688);                   // [4][64]
  float* cs2   = (float*)(smem + 51712);                   // [4][64]
  float* wpart = (float*)(smem + 52736);                   // [4][2]
  unsigned short* hL  = (unsigned short*)smem;             // alias A: [256][68] bf16 h
  unsigned short* lgL = (unsigned short*)(smem + 36864);   // alias B: [256][22] bf16 logits

  const int t = threadIdx.x;
  const int wv = t >> 6;
  const int L = t & 63;
  const int colL = L & 15;
  const int quad = L >> 4;
  const long long base = (long long)blockIdx.x * MT;

  // stage feat -> bf16 LDS (coalesced float4; LDS 2-way = free)
  {
    const float4* fsrc = (const float4*)(feat + base * C);
#pragma unroll
    for (int i = 0; i < 16; ++i) {
      int g = t + i * 256;
      float4 v = fsrc[g];
      ushort4 o;
      o.x = f2bf16(v.x); o.y = f2bf16(v.y); o.z = f2bf16(v.z); o.w = f2bf16(v.w);
      *(ushort4*)(As + (g >> 4) * ASTR + (g & 15) * 4) = o;
    }
  }
  // stage W1^T (rows = out channel j, cols = k)
#pragma unroll
  for (int i = 0; i < 16; ++i) {
    int e = t + i * 256;                       // e = k*64 + j
    Bs[(e & 63) * ASTR + (e >> 6)] = f2bf16(W1[e]);
  }
  // stage Wseg^T padded to 32 output cols (pad rows zero)
#pragma unroll
  for (int i = 0; i < 8; ++i) {
    int e = t + i * 256;                       // e over 64x32
    int k = e >> 5, j = e & 31;
    float v = (j < K) ? Wseg[k * K + j] : 0.0f;
    Bs[(64 + j) * ASTR + k] = f2bf16(v);
  }
  __syncthreads();

  // MFMA: wave wv computes rows [wv*64, wv*64+64), col tiles 0..3 = h, 4..5 = logits
  f32x4 accr[4][6];
#pragma unroll
  for (int rt = 0; rt < 4; ++rt)
#pragma unroll
    for (int ct = 0; ct < 6; ++ct) accr[rt][ct] = (f32x4){0.f, 0.f, 0.f, 0.f};

  const int rbase = wv * 64;
#pragma unroll
  for (int kh = 0; kh < 2; ++kh) {
    const int k0 = kh * 32 + quad * 8;
    bf16x8 a[4], b[6];
#pragma unroll
    for (int rt = 0; rt < 4; ++rt)
      a[rt] = *(const bf16x8*)(As + (rbase + rt * 16 + colL) * ASTR + k0);
#pragma unroll
    for (int ct = 0; ct < 6; ++ct)
      b[ct] = *(const bf16x8*)(Bs + (ct * 16 + colL) * ASTR + k0);
#pragma unroll
    for (int rt = 0; rt < 4; ++rt)
#pragma unroll
      for (int ct = 0; ct < 6; ++ct)
        accr[rt][ct] = __builtin_amdgcn_mfma_f32_16x16x32_bf16(a[rt], b[ct], accr[rt][ct], 0, 0, 0);
  }
  __syncthreads();   // all frag reads done: safe to alias A->hL, B->lgL

  // C-layout (col=lane&15, row=quad*4+reg): write h + logits to LDS, accumulate stats
  float s1[4] = {0, 0, 0, 0}, s2[4] = {0, 0, 0, 0};
#pragma unroll
  for (int rt = 0; rt < 4; ++rt) {
    const int row0 = rbase + rt * 16 + quad * 4;
#pragma unroll
    for (int ct = 0; ct < 4; ++ct) {
#pragma unroll
      for (int r = 0; r < 4; ++r) {
        float v = accr[rt][ct][r];
        s1[ct] += v;
        s2[ct] = __builtin_fmaf(v, v, s2[ct]);
        hL[(row0 + r) * HSTR + ct * 16 + colL] = f2bf16(v);
      }
    }
#pragma unroll
    for (int r = 0; r < 4; ++r) {
      lgL[(row0 + r) * LGSTR + colL] = f2bf16(accr[rt][4][r]);
      if (colL < K - 16) lgL[(row0 + r) * LGSTR + 16 + colL] = f2bf16(accr[rt][5][r]);
    }
  }
#pragma unroll
  for (int ct = 0; ct < 4; ++ct) {
    float a1 = s1[ct]; a1 += __shfl_xor(a1, 16, 64); a1 += __shfl_xor(a1, 32, 64);
    float a2 = s2[ct]; a2 += __shfl_xor(a2, 16, 64); a2 += __shfl_xor(a2, 32, 64);
    if (L < 16) { cs1[wv * 64 + ct * 16 + colL] = a1; cs2[wv * 64 + ct * 16 + colL] = a2; }
  }
  __syncthreads();

  // CE per-thread from LDS logits (row t)
  {
    float lg[K];
    const unsigned* lrow = (const unsigned*)lgL + t * (LGSTR / 2);
#pragma unroll
    for (int u = 0; u < K / 2; ++u) {
      unsigned q = lrow[u];
      lg[2 * u]     = bf16lo(q) + bseg[2 * u];
      lg[2 * u + 1] = bf16hi(q) + bseg[2 * u + 1];
    }
    const int seg = segment[base + t];
    const bool valid = (seg != -1);
    const int tgt = valid ? seg : 0;
    float mx = lg[0], lt = lg[0];
#pragma unroll
    for (int c = 1; c < K; ++c) { mx = fmaxf(mx, lg[c]); lt = (c == tgt) ? lg[c] : lt; }
    float se = 0.f;
#pragma unroll
    for (int c = 0; c < K; ++c) se += __expf(lg[c] - mx);
    float nll = mx + __logf(se) - lt;
    float w = valid ? cw[tgt] : 0.f;
    float rwn = wave_reduce_add(w * nll);
    float rw = wave_reduce_add(w);
    if (L == 0) { wpart[wv * 2] = rwn; wpart[wv * 2 + 1] = rw; }
  }

  // coalesced bf16 h spill (8 B/lane)
  if (store_h) {
#pragma unroll
    for (int i = 0; i < 16; ++i) {
      int g = t + i * 256;
      ushort4 o = *(const ushort4*)(hL + (g >> 4) * HSTR + (g & 15) * 4);
      *(ushort4*)(hout + base * C + (long long)g * 4) = o;
    }
  }
  __syncthreads();

  if (t == 0) {
    atomicAdd(&acc[0], wpart[0] + wpart[2] + wpart[4] + wpart[6]);
    atomicAdd(&acc[1], wpart[1] + wpart[3] + wpart[5] + wpart[7]);
  }
  if (t < C) {
    atomicAdd(&acc[8 + t],  cs1[t] + cs1[64 + t] + cs1[128 + t] + cs1[192 + t]);
    atomicAdd(&acc[72 + t], cs2[t] + cs2[64 + t] + cs2[128 + t] + cs2[192 + t]);
  }
}

// ---------------- prep: fold BN stats into scale/shift once ----------------

__global__ void prep_kernel(const float* __restrict__ gamma,
                            const float* __restrict__ beta,
                            float* __restrict__ acc, int n) {
  int j = threadIdx.x;
  float inv_n = 1.0f / (float)n;
  float mean = acc[8 + j] * inv_n;
  float var = fmaxf(acc[72 + j] * inv_n - mean * mean, 0.0f);
  float sc = gamma[j] * rsqrtf(var + 1e-3f);
  acc[136 + j] = sc;
  acc[200 + j] = beta[j] - mean * sc;
}

// ---------------- pass 2: coalesced staged BN+ReLU+GEMV + losses ----------------

__global__ __launch_bounds__(256)
void pass2_from_h(const unsigned short* __restrict__ hsrc,
                  const float* __restrict__ coord,
                  const int* __restrict__ instance,
                  const float* __restrict__ centroid,
                  const float* __restrict__ W2,
                  const float* __restrict__ b2,
                  float* __restrict__ acc, int n) {
  __shared__ __align__(16) unsigned short hL[MT * HSTR];
  __shared__ float part[4][3];
  const int t = threadIdx.x;
  const int wv = t >> 6, L = t & 63;
  const long long base = (long long)blockIdx.x * MT;

  // stage bf16 h tile, lane-consecutive ushort4 (coalesced 8 B/lane)
  {
    const ushort4* src = (const ushort4*)(hsrc + base * C);
#pragma unroll
    for (int i = 0; i < 16; ++i) {
      int g = t + i * 256;
      *(ushort4*)(hL + (g >> 4) * HSTR + (g & 15) * 4) = src[g];
    }
  }
  __syncthreads();

  const float* ssc = acc + 136;   // uniform addrs -> s_load
  const float* ssh = acc + 200;
  float bp0 = b2[0], bp1 = b2[1], bp2 = b2[2];
#pragma unroll
  for (int u = 0; u < 16; ++u) {
    ushort4 q = *(const ushort4*)(hL + t * HSTR + u * 4);
    unsigned short qq[4] = { q.x, q.y, q.z, q.w };
#pragma unroll
    for (int e = 0; e < 4; ++e) {
      int j = u * 4 + e;
      float v = __uint_as_float((unsigned)qq[e] << 16);
      float y = fmaxf(__builtin_fmaf(v, ssc[j], ssh[j]), 0.0f);
      bp0 = __builtin_fmaf(y, W2[j * 3 + 0], bp0);
      bp1 = __builtin_fmaf(y, W2[j * 3 + 1], bp1);
      bp2 = __builtin_fmaf(y, W2[j * 3 + 2], bp2);
    }
  }

  const long long p = base + t;
  float l1m, cosm, m;
  point_losses(p, bp0, bp1, bp2, coord, instance, centroid, l1m, cosm, m);
  float r0 = wave_reduce_add(l1m);
  float r1 = wave_reduce_add(cosm);
  float r2 = wave_reduce_add(m);
  if (L == 0) { part[wv][0] = r0; part[wv][1] = r1; part[wv][2] = r2; }
  __syncthreads();
  if (t == 0) {
    float a0 = 0, a1 = 0, a2 = 0;
#pragma unroll
    for (int w = 0; w < 4; ++w) { a0 += part[w][0]; a1 += part[w][1]; a2 += part[w][2]; }
    atomicAdd(&acc[2], a0);
    atomicAdd(&acc[3], a1);
    atomicAdd(&acc[4], a2);
  }
}

// ---------------- pass 2 fallback: recompute h from feat (no spill space) ----------------

__global__ __launch_bounds__(P1_TPB, 2)
void pass2_recompute(const float* __restrict__ feat,
                     const float* __restrict__ coord,
                     const int* __restrict__ instance,
                     const float* __restrict__ centroid,
                     const float* __restrict__ W1,
                     const float* __restrict__ W2,
                     const float* __restrict__ b2,
                     float* __restrict__ acc, int n) {
  __shared__ float lds[P1_ROWS * LSTR];
  __shared__ float part[2][3];
  const int tid = threadIdx.x;
  const int wave = tid >> 6;
  const int lane = tid & 63;
  const long long base = (long long)blockIdx.x * P1_ROWS;

  {
    const float4* src = (const float4*)(feat + base * C);
#pragma unroll
    for (int i = 0; i < 16; ++i) {
      int g = tid + i * P1_TPB;
      float4 v = src[g];
      float* d = &lds[(g >> 4) * LSTR + ((g & 15) << 2)];
      d[0] = v.x; d[1] = v.y; d[2] = v.z; d[3] = v.w;
    }
  }
  __syncthreads();

  float h[C];
#pragma unroll
  for (int j = 0; j < C; ++j) h[j] = 0.0f;   // b1 dropped (BN shift-invariant)
  const float* frow = &lds[tid * LSTR];
#pragma unroll 4
  for (int k = 0; k < C; ++k) {
    float fk = frow[k];
#pragma unroll
    for (int j = 0; j < C; ++j) h[j] = __builtin_fmaf(fk, W1[k * C + j], h[j]);
  }

  const float* ssc = acc + 136;
  const float* ssh = acc + 200;
  float bp0 = b2[0], bp1 = b2[1], bp2 = b2[2];
#pragma unroll
  for (int j = 0; j < C; ++j) {
    float y = fmaxf(__builtin_fmaf(h[j], ssc[j], ssh[j]), 0.0f);
    bp0 = __builtin_fmaf(y, W2[j * 3 + 0], bp0);
    bp1 = __builtin_fmaf(y, W2[j * 3 + 1], bp1);
    bp2 = __builtin_fmaf(y, W2[j * 3 + 2], bp2);
  }

  const long long p = base + tid;
  float l1m, cosm, m;
  point_losses(p, bp0, bp1, bp2, coord, instance, centroid, l1m, cosm, m);
  float r0 = wave_reduce_add(l1m);
  float r1 = wave_reduce_add(cosm);
  float r2 = wave_reduce_add(m);
  if (lane == 0) { part[wave][0] = r0; part[wave][1] = r1; part[wave][2] = r2; }
  __syncthreads();
  if (tid == 0) {
    atomicAdd(&acc[2], part[0][0] + part[1][0]);
    atomicAdd(&acc[3], part[0][1] + part[1][1]);
    atomicAdd(&acc[4], part[0][2] + part[1][2]);
  }
}

// ---------------- finalize ----------------

__global__ void finalize_kernel(const float* __restrict__ acc, float* __restrict__ out) {
  if (threadIdx.x == 0 && blockIdx.x == 0) {
    float seg = acc[0] / acc[1];
    float den = acc[4] + 1e-8f;
    float l1 = acc[2] / den;
    float cs = acc[3] / den;
    out[0] = seg + l1 + cs;
    out[1] = seg;
    out[2] = l1;
    out[3] = cs;
  }
}

// ---------------- launch ----------------

extern "C" void kernel_launch(void* const* d_in, const int* in_sizes, int n_in,
                              void* d_out, int out_size, void* d_ws, size_t ws_size,
                              hipStream_t stream) {
  const float* feat = (const float*)d_in[0];
  const float* coord = (const float*)d_in[1];
  const int* segment = (const int*)d_in[2];
  const int* instance = (const int*)d_in[3];
  const float* centroid = (const float*)d_in[4];
  const float* W1 = (const float*)d_in[5];
  // d_in[6] = b1 : unused (BN train-mode output is invariant to channel shift)
  const float* gamma = (const float*)d_in[7];
  const float* beta = (const float*)d_in[8];
  const float* W2 = (const float*)d_in[9];
  const float* b2 = (const float*)d_in[10];
  const float* Wseg = (const float*)d_in[11];
  const float* bseg = (const float*)d_in[12];
  const float* cw = (const float*)d_in[13];

  const int n = in_sizes[0] / C;  // 1048576

  float* acc = (float*)d_ws;
  unsigned short* hbuf = (unsigned short*)((char*)d_ws + 2048);
  const size_t need = 2048 + (size_t)n * C * sizeof(unsigned short);
  const int store_h = (ws_size >= need) ? 1 : 0;

  size_t zbytes = ws_size < 2048 ? ws_size : 2048;
  hipMemsetAsync(d_ws, 0, zbytes, stream);

  pass1_kernel<<<n / MT, 256, 0, stream>>>(feat, segment, W1, Wseg, bseg, cw,
                                           acc, hbuf, store_h, n);
  prep_kernel<<<1, 64, 0, stream>>>(gamma, beta, acc, n);
  if (store_h) {
    pass2_from_h<<<n / MT, 256, 0, stream>>>(hbuf, coord, instance, centroid,
                                             W2, b2, acc, n);
  } else {
    pass2_recompute<<<n / P1_ROWS, P1_TPB, 0, stream>>>(feat, coord, instance, centroid,
                                                        W1, W2, b2, acc, n);
  }
  finalize_kernel<<<1, 1, 0, stream>>>(acc, (float*)d_out);
}